// Round 2
// baseline (445.540 us; speedup 1.0000x reference)
//
#include <hip/hip_runtime.h>
#include <math.h>

#define CIN 256
#define SEQ 1024
#define HID 512

typedef __attribute__((ext_vector_type(8))) short short8;
typedef __attribute__((ext_vector_type(4))) short short4v;
typedef __attribute__((ext_vector_type(4))) float float4v;

static __device__ inline short f2bf(float x) {  // RNE
    union { float f; unsigned u; } c; c.f = x;
    unsigned r = (c.u + 0x7FFFu + ((c.u >> 16) & 1u)) >> 16;
    return (short)r;
}
static __device__ inline float bf2f(short h) {
    union { unsigned u; float f; } c; c.u = ((unsigned)(unsigned short)h) << 16;
    return c.f;
}

// ---- per-b dependency counters: 64B-strided to avoid one-line contention ----
#define CSTRIDE 16  // 16 u32 = 64 B per counter

static __device__ inline void arrive(unsigned* c) {
    __syncthreads();  // all block stores drained (vmcnt(0) before s_barrier)
    if (threadIdx.x == 0) {
        __threadfence();  // agent fence: writeback local L2 to coherent point
        __hip_atomic_fetch_add(c, 1u, __ATOMIC_RELEASE, __HIP_MEMORY_SCOPE_AGENT);
    }
}
static __device__ inline void wait_cnt(unsigned* c, unsigned target) {
    if (threadIdx.x == 0) {
        while (__hip_atomic_load(c, __ATOMIC_RELAXED, __HIP_MEMORY_SCOPE_AGENT) < target)
            __builtin_amdgcn_s_sleep(8);  // ~512 cy per poll
        __threadfence();  // acquire side: invalidate L1/L2 before data reads
    }
    __syncthreads();
}

// ============ K0: weight packs + ssq zero + counter zero ====================
__global__ __launch_bounds__(256) void init_pack(const float* __restrict__ w_qkv,
                                                 const float* __restrict__ w_out,
                                                 short* __restrict__ wqp,
                                                 short* __restrict__ wpk,
                                                 float* __restrict__ ssq,
                                                 unsigned* __restrict__ ctr) {
    const int t = threadIdx.x, lane = t & 63, wv = t >> 6;
    const int bx = blockIdx.x;
    const int c = lane & 15, q = lane >> 4;
    if (bx < 192) {
        const int fid = bx * 4 + wv;  // 0..767
        const int m = (fid >> 3) * 16 + c;
        const int k0 = (fid & 7) * 32 + q * 8;
        const float* p = w_qkv + (size_t)m * CIN + k0;
        float4v lo = *(const float4v*)p;
        float4v hi = *(const float4v*)(p + 4);
        short8 v;
#pragma unroll
        for (int e = 0; e < 4; ++e) { v[e] = f2bf(lo[e]); v[4 + e] = f2bf(hi[e]); }
        *(short8*)(wqp + (size_t)fid * 512 + lane * 8) = v;
    } else if (bx < 256) {
        const int fid = (bx - 192) * 4 + wv;  // 0..255
        const int m = (fid >> 4) * 16 + c;
        const int k0 = (fid & 15) * 32 + q * 8;
        const float* p = w_out + (size_t)m * HID + k0;
        float4v lo = *(const float4v*)p;
        float4v hi = *(const float4v*)(p + 4);
        short8 v;
#pragma unroll
        for (int e = 0; e < 4; ++e) { v[e] = f2bf(lo[e]); v[4 + e] = f2bf(hi[e]); }
        *(short8*)(wpk + (size_t)fid * 512 + lane * 8) = v;
    } else {
        float4v z = (float4v){0.f, 0.f, 0.f, 0.f};
#pragma unroll
        for (int k = 0; k < 8; ++k) *((float4v*)ssq + t * 8 + k) = z;
        for (int k = t; k < 24 * CSTRIDE; k += 256) ctr[k] = 0u;
    }
}

// ============ phase bodies (item-indexed, formerly separate kernels) ========
static __device__ void pack_x_item(const float* __restrict__ x, short* __restrict__ xp,
                                   int bx) {
    const int t = threadIdx.x, lane = t & 63, wv = t >> 6;
    const int c = lane & 15, q = lane >> 4;
    const int fid = bx * 4 + wv;  // 0..4095
    const int b = fid >> 9, kt = (fid >> 6) & 7, nt = fid & 63;
    const float* src = x + ((size_t)(b * 256 + kt * 32 + q * 8)) * SEQ + nt * 16 + c;
    short8 v;
#pragma unroll
    for (int e = 0; e < 8; ++e) v[e] = f2bf(src[(size_t)e * SEQ]);
    *(short8*)(xp + (size_t)fid * 512 + lane * 8) = v;
}

static __device__ void qkv_item(const short* __restrict__ xp, const short* __restrict__ wqp,
                                short* __restrict__ qp, short* __restrict__ kp,
                                short* __restrict__ vp, float* __restrict__ ssq, int it) {
    const int t = threadIdx.x, lane = t & 63, wv = t >> 6;
    const int c = lane & 15, q = lane >> 4;
    const int b = it / 192;
    const int zh = ((it >> 5) % 6) * 4 + wv;  // 0..23
    const int zone = zh >> 3, h = zh & 7;
    const int bh = b * 8 + h;
    const int nt0 = (it & 31) * 2;            // 2 n-tiles = 32 s

    const short* bp = xp + ((size_t)b * 512 + nt0) * 512 + lane * 8;
    const short* ap = wqp + (size_t)zh * 32 * 512 + lane * 8;

    float4v acc[4][2];
#pragma unroll
    for (int i = 0; i < 4; ++i)
#pragma unroll
        for (int j = 0; j < 2; ++j) acc[i][j] = (float4v){0.f, 0.f, 0.f, 0.f};

#pragma unroll 2
    for (int kt = 0; kt < 8; ++kt) {
        short8 bfr[2], af[4];
#pragma unroll
        for (int j = 0; j < 2; ++j)
            bfr[j] = *(const short8*)(bp + ((size_t)kt * 64 + j) * 512);
#pragma unroll
        for (int i = 0; i < 4; ++i)
            af[i] = *(const short8*)(ap + (size_t)(i * 8 + kt) * 512);
        if (zone < 2) {
#pragma unroll
            for (int i = 0; i < 4; ++i)
#pragma unroll
                for (int j = 0; j < 2; ++j)
                    acc[i][j] = __builtin_amdgcn_mfma_f32_16x16x32_bf16(af[i], bfr[j],
                                                                        acc[i][j], 0, 0, 0);
        } else {
#pragma unroll
            for (int i = 0; i < 4; ++i)
#pragma unroll
                for (int j = 0; j < 2; ++j)
                    acc[i][j] = __builtin_amdgcn_mfma_f32_16x16x32_bf16(bfr[j], af[i],
                                                                        acc[i][j], 0, 0, 0);
        }
    }

    if (zone < 2) {
#pragma unroll
        for (int r = 0; r < 4; ++r) {
            const int d = q * 4 + r;
            const float invf = exp2f(-(float)d * 0.83048202372184045f);  // 10000^(-d/16)
#pragma unroll
            for (int j = 0; j < 2; ++j) {
                float ang = (float)((nt0 + j) * 16 + c) * invf;
                float sn, cs;
                __sincosf(ang, &sn, &cs);
                float v0 = acc[0][j][r], v1 = acc[1][j][r];
                acc[0][j][r] = v0 * cs - v1 * sn;
                acc[1][j][r] = v1 * cs + v0 * sn;
            }
        }
        float* sq = ssq + (size_t)b * 1024 + zone * 512 + h * 64;
#pragma unroll
        for (int i = 0; i < 4; ++i)
#pragma unroll
            for (int r = 0; r < 4; ++r) {
                float val = 0.f;
#pragma unroll
                for (int j = 0; j < 2; ++j) val += acc[i][j][r] * acc[i][j][r];
#pragma unroll
                for (int o = 1; o < 16; o <<= 1) val += __shfl_xor(val, o, 64);
                if (c == 0) atomicAdd(&sq[i * 16 + q * 4 + r], val);
            }
        short* dst = (zone ? kp : qp) + (size_t)bh * 65536;
        const int e0 = (q & 1) * 4;
#pragma unroll
        for (int i = 0; i < 4; ++i) {
            const int st = i >> 1;
            const int qp_ = (2 * i + (q >> 1)) & 3;
#pragma unroll
            for (int j = 0; j < 2; ++j) {
                const int slice = nt0 + j;
                short4v s4;
#pragma unroll
                for (int r = 0; r < 4; ++r) s4[r] = f2bf(acc[i][j][r]);
                *(short4v*)(dst + (((size_t)slice * 2 + st) * 64 + qp_ * 16 + c) * 8 + e0) = s4;
            }
        }
    } else {
        short* dst = vp + (size_t)bh * 65536;
        const int e0 = (q & 1) * 4;
#pragma unroll
        for (int j = 0; j < 2; ++j) {
            const int jt = (nt0 + j) >> 1;
            const int qpart = ((nt0 + j) * 2 + (q >> 1)) & 3;
#pragma unroll
            for (int i = 0; i < 4; ++i) {
                short4v s4;
#pragma unroll
                for (int r = 0; r < 4; ++r) s4[r] = f2bf(acc[i][j][r]);
                *(short4v*)(dst + (((size_t)jt * 4 + i) * 64 + qpart * 16 + c) * 8 + e0) = s4;
            }
        }
    }
}

static __device__ void attn_item(const short* __restrict__ qp, const short* __restrict__ kp,
                                 const short* __restrict__ vp, const float* __restrict__ ssq,
                                 short* __restrict__ aop, int it,
                                 short (*pt)[16][40], float4v (*red)[64][9]) {
    const int t = threadIdx.x, lane = t & 63, wv = t >> 6;
    const int bh = it >> 4, b = bh >> 3, h = bh & 7;
    const int pair = wv >> 1, jhalf = wv & 1;
    const int it0 = ((it & 15) * 2 + pair) * 2;  // 2 i-tiles per wave pair
    const int c = lane & 15, q = lane >> 4;

    const float* sq_q = ssq + (size_t)b * 1024 + h * 64;
    const float* sq_k = sq_q + 512;
    float scl[2][8];
#pragma unroll
    for (int st = 0; st < 2; ++st) {
        const int d0 = st * 32 + q * 8;
        float4v q0 = *(const float4v*)(sq_q + d0);
        float4v q1 = *(const float4v*)(sq_q + d0 + 4);
        float4v k0 = *(const float4v*)(sq_k + d0);
        float4v k1 = *(const float4v*)(sq_k + d0 + 4);
#pragma unroll
        for (int e = 0; e < 4; ++e) {
            scl[st][e] = 10.f * rsqrtf(q0[e] * k0[e]);
            scl[st][4 + e] = 10.f * rsqrtf(q1[e] * k1[e]);
        }
    }

    short8 aq[2][2];
#pragma unroll
    for (int u = 0; u < 2; ++u) {
        const short* qpb = qp + (size_t)bh * 65536 + (size_t)(it0 + u) * 1024 + lane * 8;
#pragma unroll
        for (int st = 0; st < 2; ++st) {
            short8 raw = *(const short8*)(qpb + st * 512);
#pragma unroll
            for (int e = 0; e < 8; ++e) aq[u][st][e] = f2bf(bf2f(raw[e]) * scl[st][e]);
        }
    }

    short8 ones;
#pragma unroll
    for (int e = 0; e < 8; ++e) ones[e] = (short)0x3F80;  // bf16(1.0)

    float4v acc[2][4], accS[2];
#pragma unroll
    for (int u = 0; u < 2; ++u) {
        accS[u] = (float4v){0.f, 0.f, 0.f, 0.f};
#pragma unroll
        for (int dt = 0; dt < 4; ++dt) acc[u][dt] = (float4v){0.f, 0.f, 0.f, 0.f};
    }

    const int jt0 = jhalf * 16;
    for (int jt = jt0; jt < jt0 + 16; ++jt) {
        const short* kbb = kp + (size_t)bh * 65536 + (size_t)jt * 2048 + lane * 8;
        short8 bk00 = *(const short8*)kbb;
        short8 bk01 = *(const short8*)(kbb + 512);
        short8 bk10 = *(const short8*)(kbb + 1024);
        short8 bk11 = *(const short8*)(kbb + 1536);
        const short* vbb = vp + (size_t)bh * 65536 + (size_t)jt * 2048 + lane * 8;
        short8 bv0 = *(const short8*)vbb;
        short8 bv1 = *(const short8*)(vbb + 512);
        short8 bv2 = *(const short8*)(vbb + 1024);
        short8 bv3 = *(const short8*)(vbb + 1536);

#pragma unroll
        for (int u = 0; u < 2; ++u) {
            float4v s0 = (float4v){0.f, 0.f, 0.f, 0.f};
            float4v s1 = (float4v){0.f, 0.f, 0.f, 0.f};
            s0 = __builtin_amdgcn_mfma_f32_16x16x32_bf16(bk00, aq[u][0], s0, 0, 0, 0);
            s0 = __builtin_amdgcn_mfma_f32_16x16x32_bf16(bk01, aq[u][1], s0, 0, 0, 0);
            s1 = __builtin_amdgcn_mfma_f32_16x16x32_bf16(bk10, aq[u][0], s1, 0, 0, 0);
            s1 = __builtin_amdgcn_mfma_f32_16x16x32_bf16(bk11, aq[u][1], s1, 0, 0, 0);

            int* ptw = (int*)&pt[wv][c][0];
#pragma unroll
            for (int jh = 0; jh < 2; ++jh) {
                float4v s = jh ? s1 : s0;
                unsigned u0 = __float_as_uint(__expf(s[0]));
                unsigned u1 = __float_as_uint(__expf(s[1]));
                unsigned u2 = __float_as_uint(__expf(s[2]));
                unsigned u3 = __float_as_uint(__expf(s[3]));
                ptw[jh * 8 + q * 2]     = (int)((u1 & 0xFFFF0000u) | (u0 >> 16));
                ptw[jh * 8 + q * 2 + 1] = (int)((u3 & 0xFFFF0000u) | (u2 >> 16));
            }
            short8 apf = *(const short8*)&pt[wv][c][q * 8];  // P[i=c][j=q*8+e]

            acc[u][0] = __builtin_amdgcn_mfma_f32_16x16x32_bf16(bv0, apf, acc[u][0], 0, 0, 0);
            acc[u][1] = __builtin_amdgcn_mfma_f32_16x16x32_bf16(bv1, apf, acc[u][1], 0, 0, 0);
            acc[u][2] = __builtin_amdgcn_mfma_f32_16x16x32_bf16(bv2, apf, acc[u][2], 0, 0, 0);
            acc[u][3] = __builtin_amdgcn_mfma_f32_16x16x32_bf16(bv3, apf, acc[u][3], 0, 0, 0);
            accS[u]   = __builtin_amdgcn_mfma_f32_16x16x32_bf16(ones, apf, accS[u], 0, 0, 0);
        }
    }

    if (jhalf) {
#pragma unroll
        for (int u = 0; u < 2; ++u)
#pragma unroll
            for (int dt = 0; dt < 4; ++dt) red[pair][lane][u * 4 + dt] = acc[u][dt];
        red[pair][lane][8] = (float4v){accS[0][0], accS[1][0], 0.f, 0.f};
    }
    __syncthreads();
    if (!jhalf) {
#pragma unroll
        for (int u = 0; u < 2; ++u)
#pragma unroll
            for (int dt = 0; dt < 4; ++dt) {
                float4v o = red[pair][lane][u * 4 + dt];
                acc[u][dt][0] += o[0]; acc[u][dt][1] += o[1];
                acc[u][dt][2] += o[2]; acc[u][dt][3] += o[3];
            }
        float4v sv = red[pair][lane][8];
        float invs[2];
        invs[0] = 1.0f / (accS[0][0] + sv[0]);
        invs[1] = 1.0f / (accS[1][0] + sv[1]);

        short* ab = aop + (size_t)b * 524288;
        const int e0 = (q & 1) * 4;
#pragma unroll
        for (int u = 0; u < 2; ++u) {
            const int itile = it0 + u;
            const float inv = invs[u];
#pragma unroll
            for (int dt = 0; dt < 4; ++dt) {
                const int kt = h * 2 + (dt >> 1);
                const int ln = ((dt * 2 + (q >> 1)) & 3) * 16 + c;
                short4v s4;
#pragma unroll
                for (int r = 0; r < 4; ++r) s4[r] = f2bf(acc[u][dt][r] * inv);
                *(short4v*)(ab + (((size_t)kt * 64 + itile) * 64 + ln) * 8 + e0) = s4;
            }
        }
    }
}

static __device__ void out_item(const short* __restrict__ wp, const short* __restrict__ aop,
                                const float* __restrict__ bias, float* __restrict__ out,
                                int it) {
    const int t = threadIdx.x, lane = t & 63, w = t >> 6;
    const int nt = it & 63, b = (it >> 6) & 7, mh = it >> 9;
    const int c = lane & 15, q = lane >> 4;

    const short* bp = aop + ((size_t)b * 1024 + nt) * 512 + lane * 8;
    const short* ap = wp + (size_t)lane * 8;

    float4v acc[2];
#pragma unroll
    for (int i = 0; i < 2; ++i) acc[i] = (float4v){0.f, 0.f, 0.f, 0.f};

#pragma unroll 4
    for (int kt = 0; kt < 16; ++kt) {
        short8 bf_ = *(const short8*)(bp + (size_t)kt * 32768);
#pragma unroll
        for (int i = 0; i < 2; ++i) {
            const int mt = mh * 8 + w * 2 + i;
            short8 af = *(const short8*)(ap + (size_t)(mt * 16 + kt) * 512);
            acc[i] = __builtin_amdgcn_mfma_f32_16x16x32_bf16(af, bf_, acc[i], 0, 0, 0);
        }
    }

    float* ob = out + (size_t)b * CIN * SEQ;
#pragma unroll
    for (int i = 0; i < 2; ++i)
#pragma unroll
        for (int r = 0; r < 4; ++r) {
            const int o = (mh * 8 + w * 2 + i) * 16 + q * 4 + r;
            ob[(size_t)o * SEQ + nt * 16 + c] = acc[i][r] + bias[o];
        }
}

// ============ mega: persistent 768-block (3/CU) b-pipelined kernel ==========
// item maps: pack 1024 (b=it>>7, 128/b) ; qkv 1536 (b=it/192, 192/b);
// attn 1024 (b=it>>7, 128/b) ; out 1024 (b=(it>>6)&7, 128/b).
// Block P does items {P, P+768<limit}; all deps point to earlier phases and
// every block finishes its earlier-phase items before any wait => no deadlock.
__global__ __launch_bounds__(256, 3) void mega(const float* __restrict__ x,
                                               short* __restrict__ xp,
                                               const short* __restrict__ wqp,
                                               short* __restrict__ qp,
                                               short* __restrict__ kp,
                                               short* __restrict__ vp,
                                               float* __restrict__ ssq,
                                               short* __restrict__ aop,
                                               const short* __restrict__ wpk,
                                               const float* __restrict__ bias,
                                               float* __restrict__ out,
                                               unsigned* __restrict__ ctr) {
    __shared__ __align__(16) short pt[4][16][40];
    __shared__ __align__(16) float4v red[2][64][9];
    const int P = blockIdx.x;
#define PACKDONE(b) (ctr + ((b)) * CSTRIDE)
#define QKVDONE(b)  (ctr + (8 + (b)) * CSTRIDE)
#define ATTNDONE(b) (ctr + (16 + (b)) * CSTRIDE)

    // ---- phase 0: pack x ----
    pack_x_item(x, xp, P);
    arrive(PACKDONE(P >> 7));
    if (P < 256) {
        pack_x_item(x, xp, P + 768);
        arrive(PACKDONE((P + 768) >> 7));
    }

    // ---- phase 1: qkv ----
    {
        int it = P, b = it / 192;
        wait_cnt(PACKDONE(b), 128);
        qkv_item(xp, wqp, qp, kp, vp, ssq, it);
        arrive(QKVDONE(b));
        it = P + 768; b = it / 192;
        wait_cnt(PACKDONE(b), 128);
        qkv_item(xp, wqp, qp, kp, vp, ssq, it);
        arrive(QKVDONE(b));
    }

    // ---- phase 2: attn ----
    {
        int it = P, b = it >> 7;
        wait_cnt(QKVDONE(b), 192);
        attn_item(qp, kp, vp, ssq, aop, it, pt, red);
        arrive(ATTNDONE(b));
        if (P < 256) {
            int it2 = P + 768, b2 = it2 >> 7;
            wait_cnt(QKVDONE(b2), 192);
            attn_item(qp, kp, vp, ssq, aop, it2, pt, red);
            arrive(ATTNDONE(b2));
        }
    }

    // ---- phase 3: out ----
    {
        int it = P, b = (it >> 6) & 7;
        wait_cnt(ATTNDONE(b), 128);
        out_item(wpk, aop, bias, out, it);
        if (P < 256) {
            int it2 = P + 768, b2 = (it2 >> 6) & 7;
            wait_cnt(ATTNDONE(b2), 128);
            out_item(wpk, aop, bias, out, it2);
        }
    }
#undef PACKDONE
#undef QKVDONE
#undef ATTNDONE
}

extern "C" void kernel_launch(void* const* d_in, const int* in_sizes, int n_in,
                              void* d_out, int out_size, void* d_ws, size_t ws_size,
                              hipStream_t stream) {
    const float* x = (const float*)d_in[0];
    const float* w_qkv = (const float*)d_in[1];
    const float* w_out = (const float*)d_in[2];
    const float* b_out = (const float*)d_in[3];
    float* out = (float*)d_out;

    char* wsp = (char*)d_ws;
    short* qp  = (short*)wsp;                        // 8.39 MB
    short* kp  = (short*)(wsp + 8388608);            // 8.39 MB
    short* vp  = (short*)(wsp + 16777216);           // 8.39 MB
    short* aop = (short*)(wsp + 25165824);           // 8.39 MB
    short* wpk = (short*)(wsp + 33554432);           // 0.26 MB
    float* ssq = (float*)(wsp + 33816576);           // 32 KB
    short* xp  = (short*)(wsp + 33849344);           // 4.19 MB
    short* wqp = (short*)(wsp + 38043648);           // 0.79 MB
    unsigned* ctr = (unsigned*)(wsp + 38830080);     // 1.5 KB counters

    init_pack<<<dim3(257), 256, 0, stream>>>(w_qkv, w_out, wqp, wpk, ssq, ctr);
    mega<<<dim3(768), 256, 0, stream>>>(x, xp, wqp, qp, kp, vp, ssq, aop, wpk,
                                        b_out, out, ctr);
}

// Round 3
// 279.139 us; speedup vs baseline: 1.5961x; 1.5961x over previous
//
#include <hip/hip_runtime.h>
#include <math.h>

#define CIN 256
#define SEQ 1024
#define HID 512

typedef __attribute__((ext_vector_type(8))) short short8;
typedef __attribute__((ext_vector_type(4))) short short4v;
typedef __attribute__((ext_vector_type(4))) float float4v;

static __device__ inline short f2bf(float x) {  // RNE
    union { float f; unsigned u; } c; c.f = x;
    unsigned r = (c.u + 0x7FFFu + ((c.u >> 16) & 1u)) >> 16;
    return (short)r;
}
static __device__ inline float bf2f(short h) {
    union { unsigned u; float f; } c; c.u = ((unsigned)(unsigned short)h) << 16;
    return c.f;
}

// ---- clustered hierarchical grid barrier (1024 blocks = 32 groups x 32) ----
// Release-writebacks happen during the arrival tail; acquire-invalidates all
// fire together once the root completes -> no scattered L2 trashing (R2 bug).
static __device__ inline void gridbar(unsigned* ctr, int s, int P) {
    __syncthreads();
    if (threadIdx.x == 0) {
        __threadfence();  // release: writeback local L2 to coherent point
        unsigned* g = ctr + (unsigned)(s * 33 + (P >> 5)) * 16;
        unsigned* root = ctr + (unsigned)(s * 33 + 32) * 16;
        unsigned v = __hip_atomic_fetch_add(g, 1u, __ATOMIC_RELAXED,
                                            __HIP_MEMORY_SCOPE_AGENT) + 1u;
        if (v == 32u)
            __hip_atomic_fetch_add(root, 1u, __ATOMIC_RELAXED,
                                   __HIP_MEMORY_SCOPE_AGENT);
        while (__hip_atomic_load(root, __ATOMIC_RELAXED,
                                 __HIP_MEMORY_SCOPE_AGENT) < 32u)
            __builtin_amdgcn_s_sleep(2);
        __threadfence();  // acquire: invalidate before reading others' data
    }
    __syncthreads();
}

// ============ mega: 1024 blocks (4/CU co-resident), 3 phases, 2 barriers ====
// Phase Q: qkv proj, x staged f32->bf16 frags in LDS (block-shared), w_qkv
//          converted inline. items 1536: b=it&7 (XCD-partition), sub=it>>3.
// Phase A: attention (R1 body). bh=(P&7)*8+(P>>7) -> XCD k owns bh k*8..k*8+7.
// Phase O: out proj, w_out converted inline. b=P&7.
__global__ __launch_bounds__(256, 4) void mega(const float* __restrict__ x,
                                               const float* __restrict__ w_qkv,
                                               const float* __restrict__ w_out,
                                               const float* __restrict__ bias,
                                               float* __restrict__ out,
                                               short* __restrict__ qp,
                                               short* __restrict__ kp,
                                               short* __restrict__ vp,
                                               float* __restrict__ ssq,
                                               short* __restrict__ aop,
                                               unsigned* __restrict__ ctr) {
    __shared__ __align__(16) char smem[24064];
    const int P = blockIdx.x;
    const int t = threadIdx.x, lane = t & 63, wv = t >> 6;
    const int c = lane & 15, q = lane >> 4;

    // ======================= phase Q: qkv =======================
    short* sx = (short*)smem;  // 16 frags x 512 shorts = 16 KB
#pragma unroll 1
    for (int pass = 0; pass < 2; ++pass) {
        if (pass && P >= 512) break;
        const int it = pass ? (1024 + P) : P;
        const int b = it & 7;
        const int sub = it >> 3;        // 0..191
        const int yg = sub % 6;
        const int nt0 = (sub / 6) * 2;  // 2 n-tiles = 32 s
        const int zh = yg * 4 + wv;     // 0..23
        const int zone = zh >> 3, h = zh & 7;
        const int bh = b * 8 + h;

        __syncthreads();  // protect LDS from previous pass readers
        // stage x-slice B-frags: wave wv -> frags wv*4..wv*4+3
#pragma unroll
        for (int f = 0; f < 4; ++f) {
            const int fid2 = wv * 4 + f;
            const int kt = fid2 >> 1, nj = fid2 & 1;
            const float* src = x + ((size_t)(b * 256 + kt * 32 + q * 8)) * SEQ
                                 + (nt0 + nj) * 16 + c;
            short8 v;
#pragma unroll
            for (int e = 0; e < 8; ++e) v[e] = f2bf(src[(size_t)e * SEQ]);
            *(short8*)(sx + fid2 * 512 + lane * 8) = v;
        }
        __syncthreads();

        float4v acc[4][2];
#pragma unroll
        for (int i = 0; i < 4; ++i)
#pragma unroll
            for (int j = 0; j < 2; ++j) acc[i][j] = (float4v){0.f, 0.f, 0.f, 0.f};

#pragma unroll 2
        for (int kt = 0; kt < 8; ++kt) {
            short8 bfr[2], af[4];
#pragma unroll
            for (int j = 0; j < 2; ++j)
                bfr[j] = *(const short8*)(sx + (kt * 2 + j) * 512 + lane * 8);
#pragma unroll
            for (int i = 0; i < 4; ++i) {
                const float* wp_ = w_qkv + (size_t)((zh * 4 + i) * 16 + c) * CIN
                                        + kt * 32 + q * 8;
                float4v lo = *(const float4v*)wp_;
                float4v hi = *(const float4v*)(wp_ + 4);
                short8 a;
#pragma unroll
                for (int e = 0; e < 4; ++e) { a[e] = f2bf(lo[e]); a[4 + e] = f2bf(hi[e]); }
                af[i] = a;
            }
            if (zone < 2) {
#pragma unroll
                for (int i = 0; i < 4; ++i)
#pragma unroll
                    for (int j = 0; j < 2; ++j)
                        acc[i][j] = __builtin_amdgcn_mfma_f32_16x16x32_bf16(af[i], bfr[j],
                                                                            acc[i][j], 0, 0, 0);
            } else {
#pragma unroll
                for (int i = 0; i < 4; ++i)
#pragma unroll
                    for (int j = 0; j < 2; ++j)
                        acc[i][j] = __builtin_amdgcn_mfma_f32_16x16x32_bf16(bfr[j], af[i],
                                                                            acc[i][j], 0, 0, 0);
            }
        }

        if (zone < 2) {
            // ---- RoPE: acc[0] rows d=q*4+r pair with acc[1] rows d+16 ----
#pragma unroll
            for (int r = 0; r < 4; ++r) {
                const int d = q * 4 + r;
                const float invf = exp2f(-(float)d * 0.83048202372184045f);  // 10000^(-d/16)
#pragma unroll
                for (int j = 0; j < 2; ++j) {
                    float ang = (float)((nt0 + j) * 16 + c) * invf;
                    float sn, cs;
                    __sincosf(ang, &sn, &cs);
                    float v0 = acc[0][j][r], v1 = acc[1][j][r];
                    acc[0][j][r] = v0 * cs - v1 * sn;
                    acc[1][j][r] = v1 * cs + v0 * sn;
                }
            }
            // ---- per-row ssq partials -> atomicAdd (ssq pre-zeroed) ----
            float* sq = ssq + (size_t)b * 1024 + zone * 512 + h * 64;
#pragma unroll
            for (int i = 0; i < 4; ++i)
#pragma unroll
                for (int r = 0; r < 4; ++r) {
                    float val = 0.f;
#pragma unroll
                    for (int j = 0; j < 2; ++j) val += acc[i][j][r] * acc[i][j][r];
#pragma unroll
                    for (int o = 1; o < 16; o <<= 1) val += __shfl_xor(val, o, 64);
                    if (c == 0) atomicAdd(&sq[i * 16 + q * 4 + r], val);
                }
            // ---- scatter roped bf16, contiguous short4 ----
            short* dst = (zone ? kp : qp) + (size_t)bh * 65536;
            const int e0 = (q & 1) * 4;
#pragma unroll
            for (int i = 0; i < 4; ++i) {
                const int st = i >> 1;
                const int qp_ = (2 * i + (q >> 1)) & 3;
#pragma unroll
                for (int j = 0; j < 2; ++j) {
                    const int slice = nt0 + j;
                    short4v s4;
#pragma unroll
                    for (int r = 0; r < 4; ++r) s4[r] = f2bf(acc[i][j][r]);
                    *(short4v*)(dst + (((size_t)slice * 2 + st) * 64 + qp_ * 16 + c) * 8 + e0) = s4;
                }
            }
        } else {
            // ---- V (transposed tiles) ----
            short* dst = vp + (size_t)bh * 65536;
            const int e0 = (q & 1) * 4;
#pragma unroll
            for (int j = 0; j < 2; ++j) {
                const int jt = (nt0 + j) >> 1;
                const int qpart = ((nt0 + j) * 2 + (q >> 1)) & 3;
#pragma unroll
                for (int i = 0; i < 4; ++i) {
                    short4v s4;
#pragma unroll
                    for (int r = 0; r < 4; ++r) s4[r] = f2bf(acc[i][j][r]);
                    *(short4v*)(dst + (((size_t)jt * 4 + i) * 64 + qpart * 16 + c) * 8 + e0) = s4;
                }
            }
        }
    }

    gridbar(ctr, 0, P);

    // ======================= phase A: attention =======================
    {
        short* ptb = (short*)smem;                       // [4][16][40] = 5120 B
        float4v* red = (float4v*)(smem + 5632);          // [9][2][64] = 18432 B
        const int bh = (P & 7) * 8 + (P >> 7), b = bh >> 3, h = bh & 7;
        const int grp = (P >> 3) & 15;
        const int pair = wv >> 1, jhalf = wv & 1;
        const int it0 = (grp * 2 + pair) * 2;  // 2 i-tiles per wave pair

        const float* sq_q = ssq + (size_t)b * 1024 + h * 64;
        const float* sq_k = sq_q + 512;
        float scl[2][8];
#pragma unroll
        for (int st = 0; st < 2; ++st) {
            const int d0 = st * 32 + q * 8;
            float4v q0 = *(const float4v*)(sq_q + d0);
            float4v q1 = *(const float4v*)(sq_q + d0 + 4);
            float4v k0 = *(const float4v*)(sq_k + d0);
            float4v k1 = *(const float4v*)(sq_k + d0 + 4);
#pragma unroll
            for (int e = 0; e < 4; ++e) {
                scl[st][e] = 10.f * rsqrtf(q0[e] * k0[e]);
                scl[st][4 + e] = 10.f * rsqrtf(q1[e] * k1[e]);
            }
        }

        short8 aq[2][2];
#pragma unroll
        for (int u = 0; u < 2; ++u) {
            const short* qpb = qp + (size_t)bh * 65536 + (size_t)(it0 + u) * 1024 + lane * 8;
#pragma unroll
            for (int st = 0; st < 2; ++st) {
                short8 raw = *(const short8*)(qpb + st * 512);
#pragma unroll
                for (int e = 0; e < 8; ++e) aq[u][st][e] = f2bf(bf2f(raw[e]) * scl[st][e]);
            }
        }

        short8 ones;
#pragma unroll
        for (int e = 0; e < 8; ++e) ones[e] = (short)0x3F80;  // bf16(1.0)

        float4v acc[2][4], accS[2];
#pragma unroll
        for (int u = 0; u < 2; ++u) {
            accS[u] = (float4v){0.f, 0.f, 0.f, 0.f};
#pragma unroll
            for (int dt = 0; dt < 4; ++dt) acc[u][dt] = (float4v){0.f, 0.f, 0.f, 0.f};
        }

        const int jt0 = jhalf * 16;
        for (int jt = jt0; jt < jt0 + 16; ++jt) {
            const short* kbb = kp + (size_t)bh * 65536 + (size_t)jt * 2048 + lane * 8;
            short8 bk00 = *(const short8*)kbb;
            short8 bk01 = *(const short8*)(kbb + 512);
            short8 bk10 = *(const short8*)(kbb + 1024);
            short8 bk11 = *(const short8*)(kbb + 1536);
            const short* vbb = vp + (size_t)bh * 65536 + (size_t)jt * 2048 + lane * 8;
            short8 bv0 = *(const short8*)vbb;
            short8 bv1 = *(const short8*)(vbb + 512);
            short8 bv2 = *(const short8*)(vbb + 1024);
            short8 bv3 = *(const short8*)(vbb + 1536);

#pragma unroll
            for (int u = 0; u < 2; ++u) {
                float4v s0 = (float4v){0.f, 0.f, 0.f, 0.f};
                float4v s1 = (float4v){0.f, 0.f, 0.f, 0.f};
                s0 = __builtin_amdgcn_mfma_f32_16x16x32_bf16(bk00, aq[u][0], s0, 0, 0, 0);
                s0 = __builtin_amdgcn_mfma_f32_16x16x32_bf16(bk01, aq[u][1], s0, 0, 0, 0);
                s1 = __builtin_amdgcn_mfma_f32_16x16x32_bf16(bk10, aq[u][0], s1, 0, 0, 0);
                s1 = __builtin_amdgcn_mfma_f32_16x16x32_bf16(bk11, aq[u][1], s1, 0, 0, 0);

                int* ptw = (int*)(ptb + wv * 640 + c * 40);
#pragma unroll
                for (int jh = 0; jh < 2; ++jh) {
                    float4v s = jh ? s1 : s0;
                    unsigned u0 = __float_as_uint(__expf(s[0]));
                    unsigned u1 = __float_as_uint(__expf(s[1]));
                    unsigned u2 = __float_as_uint(__expf(s[2]));
                    unsigned u3 = __float_as_uint(__expf(s[3]));
                    ptw[jh * 8 + q * 2]     = (int)((u1 & 0xFFFF0000u) | (u0 >> 16));
                    ptw[jh * 8 + q * 2 + 1] = (int)((u3 & 0xFFFF0000u) | (u2 >> 16));
                }
                short8 apf = *(const short8*)(ptb + wv * 640 + c * 40 + q * 8);

                acc[u][0] = __builtin_amdgcn_mfma_f32_16x16x32_bf16(bv0, apf, acc[u][0], 0, 0, 0);
                acc[u][1] = __builtin_amdgcn_mfma_f32_16x16x32_bf16(bv1, apf, acc[u][1], 0, 0, 0);
                acc[u][2] = __builtin_amdgcn_mfma_f32_16x16x32_bf16(bv2, apf, acc[u][2], 0, 0, 0);
                acc[u][3] = __builtin_amdgcn_mfma_f32_16x16x32_bf16(bv3, apf, acc[u][3], 0, 0, 0);
                accS[u]   = __builtin_amdgcn_mfma_f32_16x16x32_bf16(ones, apf, accS[u], 0, 0, 0);
            }
        }

        // ---- combine j-halves; red[slot][pair][lane]: 16B lane stride ----
        if (jhalf) {
#pragma unroll
            for (int u = 0; u < 2; ++u)
#pragma unroll
                for (int dt = 0; dt < 4; ++dt)
                    red[((u * 4 + dt) * 2 + pair) * 64 + lane] = acc[u][dt];
            red[(8 * 2 + pair) * 64 + lane] = (float4v){accS[0][0], accS[1][0], 0.f, 0.f};
        }
        __syncthreads();
        if (!jhalf) {
#pragma unroll
            for (int u = 0; u < 2; ++u)
#pragma unroll
                for (int dt = 0; dt < 4; ++dt) {
                    float4v o = red[((u * 4 + dt) * 2 + pair) * 64 + lane];
                    acc[u][dt][0] += o[0]; acc[u][dt][1] += o[1];
                    acc[u][dt][2] += o[2]; acc[u][dt][3] += o[3];
                }
            float4v sv = red[(8 * 2 + pair) * 64 + lane];
            float invs[2];
            invs[0] = 1.0f / (accS[0][0] + sv[0]);
            invs[1] = 1.0f / (accS[1][0] + sv[1]);

            short* ab = aop + (size_t)b * 524288;
            const int e0 = (q & 1) * 4;
#pragma unroll
            for (int u = 0; u < 2; ++u) {
                const int itile = it0 + u;
                const float inv = invs[u];
#pragma unroll
                for (int dt = 0; dt < 4; ++dt) {
                    const int kt = h * 2 + (dt >> 1);
                    const int ln = ((dt * 2 + (q >> 1)) & 3) * 16 + c;
                    short4v s4;
#pragma unroll
                    for (int r = 0; r < 4; ++r) s4[r] = f2bf(acc[u][dt][r] * inv);
                    *(short4v*)(ab + (((size_t)kt * 64 + itile) * 64 + ln) * 8 + e0) = s4;
                }
            }
        }
    }

    gridbar(ctr, 1, P);

    // ======================= phase O: out projection =======================
    {
        const int b = P & 7;
        const int rest = P >> 3;
        const int nt = rest & 63;
        const int mh = rest >> 6;

        const short* bp = aop + ((size_t)b * 1024 + nt) * 512 + lane * 8;

        float4v acc2[2];
#pragma unroll
        for (int i = 0; i < 2; ++i) acc2[i] = (float4v){0.f, 0.f, 0.f, 0.f};

#pragma unroll 4
        for (int kt = 0; kt < 16; ++kt) {
            short8 bf_ = *(const short8*)(bp + (size_t)kt * 32768);
#pragma unroll
            for (int i = 0; i < 2; ++i) {
                const int mt = mh * 8 + wv * 2 + i;
                const float* wp_ = w_out + (size_t)(mt * 16 + c) * HID + kt * 32 + q * 8;
                float4v lo = *(const float4v*)wp_;
                float4v hi = *(const float4v*)(wp_ + 4);
                short8 a;
#pragma unroll
                for (int e = 0; e < 4; ++e) { a[e] = f2bf(lo[e]); a[4 + e] = f2bf(hi[e]); }
                acc2[i] = __builtin_amdgcn_mfma_f32_16x16x32_bf16(a, bf_, acc2[i], 0, 0, 0);
            }
        }

        float* ob = out + (size_t)b * CIN * SEQ;
#pragma unroll
        for (int i = 0; i < 2; ++i)
#pragma unroll
            for (int r = 0; r < 4; ++r) {
                const int o = (mh * 8 + wv * 2 + i) * 16 + q * 4 + r;
                ob[(size_t)o * SEQ + nt * 16 + c] = acc2[i][r] + bias[o];
            }
    }
}

extern "C" void kernel_launch(void* const* d_in, const int* in_sizes, int n_in,
                              void* d_out, int out_size, void* d_ws, size_t ws_size,
                              hipStream_t stream) {
    const float* x = (const float*)d_in[0];
    const float* w_qkv = (const float*)d_in[1];
    const float* w_out = (const float*)d_in[2];
    const float* b_out = (const float*)d_in[3];
    float* out = (float*)d_out;

    char* wsp = (char*)d_ws;
    short* qp  = (short*)wsp;                        // 8.39 MB
    short* kp  = (short*)(wsp + 8388608);            // 8.39 MB
    short* vp  = (short*)(wsp + 16777216);           // 8.39 MB
    short* aop = (short*)(wsp + 25165824);           // 8.39 MB (ends 33554432)
    float* ssq = (float*)(wsp + 33554432);           // 32 KB
    unsigned* ctr = (unsigned*)(wsp + 33587200);     // 4.2 KB barrier counters

    // zero ssq + barrier counters in one tiny memset (graph-capturable)
    hipMemsetAsync(wsp + 33554432, 0, 36992, stream);
    mega<<<dim3(1024), 256, 0, stream>>>(x, w_qkv, w_out, b_out, out,
                                         qp, kp, vp, ssq, aop, ctr);
}